// Round 7
// baseline (2241.275 us; speedup 1.0000x reference)
//
#include <hip/hip_runtime.h>

#define TPB 256
#define CSH 11                 // nodes per coarse bucket = 2048
#define CN 2048
#define NBC_MAX 64             // max coarse buckets supported by fast path
#define STILE 8192             // edges per super-tile in passC
#define EPT (STILE / TPB)      // 32 edges per thread
#define A1S 5                  // layer-1 LDS acc stride (gcd(5,32)=1)
#define A2S 3                  // layer-2 LDS acc stride

// ---------------- coarse histogram over dst ----------------

__global__ void k_histc(const int* __restrict__ dst, int* __restrict__ bcnt, int E, int NBC) {
    __shared__ int cnt[NBC_MAX];
    if (threadIdx.x < NBC_MAX) cnt[threadIdx.x] = 0;
    __syncthreads();
    int per = (E + gridDim.x - 1) / gridDim.x;
    int s = blockIdx.x * per;
    int e = min(E, s + per);
    for (int i = s + threadIdx.x; i < e; i += TPB)
        atomicAdd(&cnt[dst[i] >> CSH], 1);
    __syncthreads();
    if (threadIdx.x < (unsigned)NBC && cnt[threadIdx.x])
        atomicAdd(&bcnt[threadIdx.x], cnt[threadIdx.x]);
}

// ---------------- exclusive scan of <=64 bucket counts ----------------

__global__ void k_scanc(const int* __restrict__ bcnt, int* __restrict__ bbase,
                        int* __restrict__ cursor, int NBC) {
    __shared__ int sh[NBC_MAX];
    int t = threadIdx.x;
    if (t < NBC) sh[t] = bcnt[t];
    __syncthreads();
    if (t <= NBC) {
        int sum = 0;
        for (int j = 0; j < t && j < NBC; j++) sum += sh[j];
        if (t < NBC) { bbase[t] = sum; cursor[t] = sum; }
        else bbase[NBC] = sum;  // == E
    }
}

// ---------------- staged coalesced partition into coarse buckets ----------------
// packed = (src << 11) | (dst & 2047)

__global__ void k_passC(const int* __restrict__ src, const int* __restrict__ dst,
                        int* __restrict__ cursor, unsigned* __restrict__ packed,
                        int E, int NBC, int epb) {
    __shared__ unsigned stage[STILE];          // 32 KB
    __shared__ int hist[NBC_MAX], lb[NBC_MAX], gb[NBC_MAX], lcur[NBC_MAX];
    int bs = blockIdx.x * epb;
    int be = min(E, bs + epb);
    for (int tb = bs; tb < be; tb += STILE) {
        int te = min(be, tb + STILE);
        if (threadIdx.x < NBC_MAX) hist[threadIdx.x] = 0;
        __syncthreads();
        unsigned pk[EPT];
        int bkv[EPT];
#pragma unroll
        for (int u = 0; u < EPT; u++) {
            int i = tb + u * TPB + (int)threadIdx.x;
            if (i < te) {
                int d = dst[i];
                int b = d >> CSH;
                pk[u] = ((unsigned)src[i] << CSH) | (unsigned)(d & (CN - 1));
                bkv[u] = b;
                atomicAdd(&hist[b], 1);
            } else bkv[u] = -1;
        }
        __syncthreads();
        if (threadIdx.x < (unsigned)NBC) {
            int b = threadIdx.x;
            int sum = 0;
            for (int j = 0; j < b; j++) sum += hist[j];   // same-addr reads broadcast
            lb[b] = sum;
            lcur[b] = sum;
            gb[b] = atomicAdd(&cursor[b], hist[b]);
        }
        __syncthreads();
#pragma unroll
        for (int u = 0; u < EPT; u++) {
            if (bkv[u] >= 0) {
                int pos = atomicAdd(&lcur[bkv[u]], 1);
                stage[pos] = pk[u];
            }
        }
        __syncthreads();
        int wid = threadIdx.x >> 6, lane = threadIdx.x & 63;
        for (int b = wid; b < NBC; b += 4) {
            int len = hist[b], l = lb[b], g = gb[b];
            for (int i = lane; i < len; i += 64)
                packed[g + i] = stage[l + i];               // coalesced runs
        }
        __syncthreads();
    }
}

// ---------------- degrees from packed (per coarse bucket, S-split) ----------------

__global__ void k_degc(const unsigned* __restrict__ packed, const int* __restrict__ bbase,
                       int* __restrict__ deg, int SD, int N) {
    __shared__ int cnt[CN];
    for (int i = threadIdx.x; i < CN; i += TPB) cnt[i] = 0;
    __syncthreads();
    int b = blockIdx.x / SD, s = blockIdx.x - b * SD;
    int e0 = bbase[b], e1 = bbase[b + 1];
    int len = e1 - e0;
    int ce0 = e0 + (int)((long long)len * s / SD);
    int ce1 = e0 + (int)((long long)len * (s + 1) / SD);
    int e = ce0 + threadIdx.x;
    for (; e + 3 * TPB < ce1; e += 4 * TPB) {
        unsigned p0 = packed[e], p1 = packed[e + TPB], p2 = packed[e + 2 * TPB], p3 = packed[e + 3 * TPB];
        atomicAdd(&cnt[p0 & (CN - 1)], 1);
        atomicAdd(&cnt[p1 & (CN - 1)], 1);
        atomicAdd(&cnt[p2 & (CN - 1)], 1);
        atomicAdd(&cnt[p3 & (CN - 1)], 1);
    }
    for (; e < ce1; e += TPB)
        atomicAdd(&cnt[packed[e] & (CN - 1)], 1);
    __syncthreads();
    int node0 = b << CSH;
    for (int i = threadIdx.x; i < CN; i += TPB)
        if (cnt[i] && node0 + i < N) atomicAdd(&deg[node0 + i], cnt[i]);
}

// ---------------- node-parallel: dis = rsqrt(deg+1); xs = x*dis ----------------

__global__ void k_prepv(const float* __restrict__ x, const int* __restrict__ deg,
                        float* __restrict__ dis, float* __restrict__ xs, int N) {
    int v = blockIdx.x * blockDim.x + threadIdx.x;
    if (v >= N) return;
    float di = rsqrtf((float)(deg[v] + 1));  // +1 self-loop
    dis[v] = di;
    float4 xv = ((const float4*)x)[v];
    xv.x *= di; xv.y *= di; xv.z *= di; xv.w *= di;
    ((float4*)xs)[v] = xv;
}

// ---------------- layer-1 edge pass: aggregate xs into 2048-node LDS acc ----------------

#define U1 4

__global__ void k_agg1c(const unsigned* __restrict__ packed, const int* __restrict__ bbase,
                        const float* __restrict__ xs, float* __restrict__ partial1, int S1) {
    __shared__ float acc[CN * A1S];   // 40 KB
    for (int i = threadIdx.x; i < CN * A1S; i += TPB) acc[i] = 0.0f;
    __syncthreads();
    int b = blockIdx.x / S1, s = blockIdx.x - b * S1;
    int e0 = bbase[b], e1 = bbase[b + 1];
    int len = e1 - e0;
    int ce0 = e0 + (int)((long long)len * s / S1);
    int ce1 = e0 + (int)((long long)len * (s + 1) / S1);
    int e = ce0 + threadIdx.x;
    for (; e + (U1 - 1) * TPB < ce1; e += U1 * TPB) {
        unsigned pk[U1];
#pragma unroll
        for (int u = 0; u < U1; u++) pk[u] = packed[e + u * TPB];
        float4 m[U1];
#pragma unroll
        for (int u = 0; u < U1; u++) m[u] = ((const float4*)xs)[pk[u] >> CSH];
#pragma unroll
        for (int u = 0; u < U1; u++) {
            float* a = &acc[(pk[u] & (CN - 1)) * A1S];
            atomicAdd(a + 0, m[u].x);
            atomicAdd(a + 1, m[u].y);
            atomicAdd(a + 2, m[u].z);
            atomicAdd(a + 3, m[u].w);
        }
    }
    for (; e < ce1; e += TPB) {
        unsigned pk = packed[e];
        float4 m = ((const float4*)xs)[pk >> CSH];
        float* a = &acc[(pk & (CN - 1)) * A1S];
        atomicAdd(a + 0, m.x);
        atomicAdd(a + 1, m.y);
        atomicAdd(a + 2, m.z);
        atomicAdd(a + 3, m.w);
    }
    __syncthreads();
    float* p = partial1 + (size_t)blockIdx.x * (CN * 4);
    for (int i = threadIdx.x; i < CN * 4; i += TPB)
        p[i] = acc[(i >> 2) * A1S + (i & 3)];
}

// ---------------- layer-1 combine: (+self)*dis -> @W1+b1 -> relu -> @W2 -> *dis ----------------

__global__ void k_comb1(const float* __restrict__ partial1, const float* __restrict__ xs,
                        const float* __restrict__ dis, const float* __restrict__ W1,
                        const float* __restrict__ b1, const float* __restrict__ W2,
                        float* __restrict__ hs2, int S1, int N) {
    __shared__ float w1[64], w2[32], bb[16];
    if (threadIdx.x < 64) w1[threadIdx.x] = W1[threadIdx.x];
    if (threadIdx.x < 32) w2[threadIdx.x] = W2[threadIdx.x];
    if (threadIdx.x < 16) bb[threadIdx.x] = b1[threadIdx.x];
    __syncthreads();
    int v = blockIdx.x * blockDim.x + threadIdx.x;
    if (v >= N) return;
    int b = v >> CSH, lv = v & (CN - 1);
    float4 sum = ((const float4*)xs)[v];   // self-loop
    for (int s = 0; s < S1; s++) {
        float4 t = ((const float4*)partial1)[(size_t)(b * S1 + s) * CN + lv];
        sum.x += t.x; sum.y += t.y; sum.z += t.z; sum.w += t.w;
    }
    float di = dis[v];
    float v0 = sum.x * di, v1 = sum.y * di, v2 = sum.z * di, v3 = sum.w * di;
    float s0 = 0.f, s1 = 0.f;
#pragma unroll
    for (int j = 0; j < 16; j++) {
        float h = v0 * w1[j] + v1 * w1[16 + j] + v2 * w1[32 + j] + v3 * w1[48 + j] + bb[j];
        h = fmaxf(h, 0.0f);
        s0 += h * w2[2 * j];
        s1 += h * w2[2 * j + 1];
    }
    ((float2*)hs2)[v] = make_float2(s0 * di, s1 * di);
}

// ---------------- layer-2 edge pass ----------------

#define U2 4

__global__ void k_agg2c(const unsigned* __restrict__ packed, const int* __restrict__ bbase,
                        const float* __restrict__ hs2, float* __restrict__ partial2, int S2) {
    __shared__ float acc[CN * A2S];   // 24 KB
    for (int i = threadIdx.x; i < CN * A2S; i += TPB) acc[i] = 0.0f;
    __syncthreads();
    int b = blockIdx.x / S2, s = blockIdx.x - b * S2;
    int e0 = bbase[b], e1 = bbase[b + 1];
    int len = e1 - e0;
    int ce0 = e0 + (int)((long long)len * s / S2);
    int ce1 = e0 + (int)((long long)len * (s + 1) / S2);
    int e = ce0 + threadIdx.x;
    for (; e + (U2 - 1) * TPB < ce1; e += U2 * TPB) {
        unsigned pk[U2];
#pragma unroll
        for (int u = 0; u < U2; u++) pk[u] = packed[e + u * TPB];
        float2 m[U2];
#pragma unroll
        for (int u = 0; u < U2; u++) m[u] = ((const float2*)hs2)[pk[u] >> CSH];
#pragma unroll
        for (int u = 0; u < U2; u++) {
            float* a = &acc[(pk[u] & (CN - 1)) * A2S];
            atomicAdd(a + 0, m[u].x);
            atomicAdd(a + 1, m[u].y);
        }
    }
    for (; e < ce1; e += TPB) {
        unsigned pk = packed[e];
        float2 m = ((const float2*)hs2)[pk >> CSH];
        float* a = &acc[(pk & (CN - 1)) * A2S];
        atomicAdd(a + 0, m.x);
        atomicAdd(a + 1, m.y);
    }
    __syncthreads();
    float* p = partial2 + (size_t)blockIdx.x * (CN * 2);
    for (int i = threadIdx.x; i < CN * 2; i += TPB)
        p[i] = acc[(i >> 1) * A2S + (i & 1)];
}

// ---------------- layer-2 combine + final bias -> out ----------------

__global__ void k_comb2(const float* __restrict__ partial2, const float* __restrict__ hs2,
                        const float* __restrict__ dis, const float* __restrict__ b2,
                        float* __restrict__ out, int S2, int N) {
    int v = blockIdx.x * blockDim.x + threadIdx.x;
    if (v >= N) return;
    int b = v >> CSH, lv = v & (CN - 1);
    float2 sum = ((const float2*)hs2)[v];   // self-loop
    for (int s = 0; s < S2; s++) {
        float2 t = ((const float2*)partial2)[(size_t)(b * S2 + s) * CN + lv];
        sum.x += t.x; sum.y += t.y;
    }
    float di = dis[v];
    ((float2*)out)[v] = make_float2(sum.x * di + b2[0], sum.y * di + b2[1]);
}

// ---------------- fallback (R1 atomic pipeline) ----------------

__global__ void k_zero_fb(int* __restrict__ p, int n) {
    int i = blockIdx.x * blockDim.x + threadIdx.x;
    if (i < n) p[i] = 0;
}
__global__ void k_deg_fb(const int* __restrict__ dst, int* __restrict__ deg, int E) {
    int i = blockIdx.x * blockDim.x + threadIdx.x;
    if (i < E) atomicAdd(&deg[dst[i]], 1);
}
__global__ void k_dis_fb(const int* __restrict__ deg, float* __restrict__ dis, int N) {
    int v = blockIdx.x * blockDim.x + threadIdx.x;
    if (v < N) dis[v] = rsqrtf((float)(deg[v] + 1));
}
__global__ void k_lin1_fb(const float* __restrict__ x, const float* __restrict__ W1,
                          const float* __restrict__ dis, float* __restrict__ hs1,
                          float* __restrict__ agg1, int N) {
    __shared__ float w[64];
    if (threadIdx.x < 64) w[threadIdx.x] = W1[threadIdx.x];
    __syncthreads();
    int v = blockIdx.x * blockDim.x + threadIdx.x;
    if (v >= N) return;
    float4 xv = ((const float4*)x)[v];
    float d = dis[v];
#pragma unroll
    for (int j = 0; j < 16; j++) {
        float h = (xv.x * w[j] + xv.y * w[16 + j] + xv.z * w[32 + j] + xv.w * w[48 + j]) * d;
        hs1[v * 16 + j] = h;
        agg1[v * 16 + j] = h;
    }
}
__global__ void k_scat1_fb(const int* __restrict__ src, const int* __restrict__ dst,
                           const float* __restrict__ hs1, float* __restrict__ agg1, int E4) {
    int t = blockIdx.x * blockDim.x + threadIdx.x;
    if (t >= E4) return;
    int e = t >> 2, q = t & 3;
    int s = src[e], d = dst[e];
    float4 m = ((const float4*)hs1)[s * 4 + q];
    float* a = agg1 + (size_t)d * 16 + q * 4;
    atomicAdd(a + 0, m.x); atomicAdd(a + 1, m.y);
    atomicAdd(a + 2, m.z); atomicAdd(a + 3, m.w);
}
__global__ void k_lin2_fb(const float* __restrict__ agg1, const float* __restrict__ dis,
                          const float* __restrict__ b1, const float* __restrict__ W2,
                          float* __restrict__ hs2, float* __restrict__ agg2, int N) {
    __shared__ float w[32];
    __shared__ float bb[16];
    if (threadIdx.x < 32) w[threadIdx.x] = W2[threadIdx.x];
    if (threadIdx.x < 16) bb[threadIdx.x] = b1[threadIdx.x];
    __syncthreads();
    int v = blockIdx.x * blockDim.x + threadIdx.x;
    if (v >= N) return;
    float d = dis[v];
    float a0 = 0.f, a1 = 0.f;
#pragma unroll
    for (int k = 0; k < 16; k++) {
        float r = fmaxf(agg1[v * 16 + k] * d + bb[k], 0.0f);
        a0 += r * w[k * 2 + 0];
        a1 += r * w[k * 2 + 1];
    }
    float2 hv = make_float2(a0 * d, a1 * d);
    ((float2*)hs2)[v] = hv;
    ((float2*)agg2)[v] = hv;
}
__global__ void k_scat2_fb(const int* __restrict__ src, const int* __restrict__ dst,
                           const float* __restrict__ hs2, float* __restrict__ agg2, int E) {
    int e = blockIdx.x * blockDim.x + threadIdx.x;
    if (e >= E) return;
    int s = src[e], d = dst[e];
    float2 m = ((const float2*)hs2)[s];
    atomicAdd(&agg2[d * 2 + 0], m.x);
    atomicAdd(&agg2[d * 2 + 1], m.y);
}
__global__ void k_out_fb(const float* __restrict__ agg2, const float* __restrict__ dis,
                         const float* __restrict__ b2, float* __restrict__ out, int N) {
    int v = blockIdx.x * blockDim.x + threadIdx.x;
    if (v >= N) return;
    float d = dis[v];
    out[v * 2 + 0] = agg2[v * 2 + 0] * d + b2[0];
    out[v * 2 + 1] = agg2[v * 2 + 1] * d + b2[1];
}

// ---------------- launch ----------------

extern "C" void kernel_launch(void* const* d_in, const int* in_sizes, int n_in,
                              void* d_out, int out_size, void* d_ws, size_t ws_size,
                              hipStream_t stream) {
    const float* x  = (const float*)d_in[0];
    const int*   ei = (const int*)d_in[1];
    const float* W1 = (const float*)d_in[2];
    const float* b1 = (const float*)d_in[3];
    const float* W2 = (const float*)d_in[4];
    const float* b2 = (const float*)d_in[5];

    const int N = in_sizes[0] / 4;   // 100000
    const int E = in_sizes[1] / 2;   // 6400000
    const int* src = ei;
    const int* dst = ei + E;
    float* outp = (float*)d_out;

    auto align = [](size_t v) { return (v + 255) & ~(size_t)255; };
    const int NBC = (N + CN - 1) >> CSH;   // 49 coarse buckets

    auto need_for = [&](int S1, int S2) {
        return align((size_t)E * 4)                       /* packed */
             + align((size_t)N * 4)                       /* dis */
             + align((size_t)N * 16)                      /* xs */
             + align((size_t)N * 8)                       /* hs2 */
             + align(((size_t)N + NBC) * 4)               /* deg + bcnt (contiguous, zeroed together) */
             + align((size_t)NBC * 4)                     /* cursor */
             + align((size_t)(NBC + 1) * 4)               /* bbase */
             + align((size_t)NBC * S1 * CN * 4 * 4)       /* partial1 */
             + align((size_t)NBC * S2 * CN * 2 * 4);      /* partial2 */
    };

    const int tiers[6][2] = {{8, 8}, {8, 4}, {4, 4}, {4, 2}, {2, 2}, {1, 1}};
    int S1 = 0, S2 = 0;
    for (int t = 0; t < 6; t++)
        if (need_for(tiers[t][0], tiers[t][1]) <= ws_size) { S1 = tiers[t][0]; S2 = tiers[t][1]; break; }

    if (S1 > 0 && NBC <= NBC_MAX && (size_t)N < (1u << 21) * CN) {
        char* ws = (char*)d_ws;
        unsigned* packed = (unsigned*)ws; ws += align((size_t)E * 4);
        float* dis  = (float*)ws; ws += align((size_t)N * 4);
        float* xs   = (float*)ws; ws += align((size_t)N * 16);
        float* hs2  = (float*)ws; ws += align((size_t)N * 8);
        int* deg    = (int*)ws;   ws += align(((size_t)N + NBC) * 4);
        int* bcnt   = deg + N;    // contiguous with deg for single memset
        int* cursor = (int*)ws;   ws += align((size_t)NBC * 4);
        int* bbase  = (int*)ws;   ws += align((size_t)(NBC + 1) * 4);
        float* partial1 = (float*)ws; ws += align((size_t)NBC * S1 * CN * 4 * 4);
        float* partial2 = (float*)ws; ws += align((size_t)NBC * S2 * CN * 2 * 4);

        const int gN = (N + TPB - 1) / TPB;
        // passC block range: ~2 super-tiles per block
        const int epb = STILE * 2;
        const int gPC = (E + epb - 1) / epb;
        const int SD = 8;  // degc split

        hipMemsetAsync(deg, 0, ((size_t)N + NBC) * 4, stream);
        k_histc<<<512, TPB, 0, stream>>>(dst, bcnt, E, NBC);
        k_scanc<<<1, NBC_MAX, 0, stream>>>(bcnt, bbase, cursor, NBC);
        k_passC<<<gPC, TPB, 0, stream>>>(src, dst, cursor, packed, E, NBC, epb);
        k_degc<<<NBC * SD, TPB, 0, stream>>>(packed, bbase, deg, SD, N);
        k_prepv<<<gN, TPB, 0, stream>>>(x, deg, dis, xs, N);
        k_agg1c<<<NBC * S1, TPB, 0, stream>>>(packed, bbase, xs, partial1, S1);
        k_comb1<<<gN, TPB, 0, stream>>>(partial1, xs, dis, W1, b1, W2, hs2, S1, N);
        k_agg2c<<<NBC * S2, TPB, 0, stream>>>(packed, bbase, hs2, partial2, S2);
        k_comb2<<<gN, TPB, 0, stream>>>(partial2, hs2, dis, b2, outp, S2, N);
    } else {
        // fallback: R1 atomic-scatter pipeline
        char* ws = (char*)d_ws;
        int*   deg  = (int*)ws;   ws += align((size_t)N * 4);
        float* dis  = (float*)ws; ws += align((size_t)N * 4);
        float* hs1  = (float*)ws; ws += align((size_t)N * 16 * 4);
        float* agg1 = (float*)ws; ws += align((size_t)N * 16 * 4);
        float* hs2  = (float*)ws; ws += align((size_t)N * 2 * 4);
        float* agg2 = (float*)ws; ws += align((size_t)N * 2 * 4);
        int gN = (N + TPB - 1) / TPB;
        int gE = (E + TPB - 1) / TPB;
        int gE4 = ((size_t)E * 4 + TPB - 1) / TPB;

        k_zero_fb<<<gN, TPB, 0, stream>>>(deg, N);
        k_deg_fb<<<gE, TPB, 0, stream>>>(dst, deg, E);
        k_dis_fb<<<gN, TPB, 0, stream>>>(deg, dis, N);
        k_lin1_fb<<<gN, TPB, 0, stream>>>(x, W1, dis, hs1, agg1, N);
        k_scat1_fb<<<gE4, TPB, 0, stream>>>(src, dst, hs1, agg1, E * 4);
        k_lin2_fb<<<gN, TPB, 0, stream>>>(agg1, dis, b1, W2, hs2, agg2, N);
        k_scat2_fb<<<gE, TPB, 0, stream>>>(src, dst, hs2, agg2, E);
        k_out_fb<<<gN, TPB, 0, stream>>>(agg2, dis, b2, outp, N);
    }
}

// Round 8
// 441.153 us; speedup vs baseline: 5.0805x; 5.0805x over previous
//
#include <hip/hip_runtime.h>

#define TPB 256
#define CSH 11                 // nodes per coarse bucket = 2048
#define CN 2048
#define NBC_MAX 64             // max coarse buckets supported by fast path
#define STILE 8192             // edges per super-tile in passC
#define EPT (STILE / TPB)      // 32 edges per thread
#define A1S 5                  // layer-1 LDS acc stride (gcd(5,32)=1)
#define A2S 3                  // layer-2 LDS acc stride

// ---------------- small utils ----------------

__global__ void k_zero(int* __restrict__ p, int n) {
    int i = blockIdx.x * blockDim.x + threadIdx.x;
    if (i < n) p[i] = 0;
}

// ---------------- coarse histogram over dst ----------------

__global__ void k_histc(const int* __restrict__ dst, int* __restrict__ bcnt, int E, int NBC) {
    __shared__ int cnt[NBC_MAX];
    if (threadIdx.x < NBC_MAX) cnt[threadIdx.x] = 0;
    __syncthreads();
    int per = (E + gridDim.x - 1) / gridDim.x;
    int s = blockIdx.x * per;
    int e = min(E, s + per);
    for (int i = s + threadIdx.x; i < e; i += TPB)
        atomicAdd(&cnt[dst[i] >> CSH], 1);
    __syncthreads();
    if (threadIdx.x < (unsigned)NBC && cnt[threadIdx.x])
        atomicAdd(&bcnt[threadIdx.x], cnt[threadIdx.x]);
}

// ---------------- exclusive scan of <=64 bucket counts ----------------

__global__ void k_scanc(const int* __restrict__ bcnt, int* __restrict__ bbase,
                        int* __restrict__ cursor, int NBC) {
    __shared__ int sh[NBC_MAX];
    int t = threadIdx.x;
    if (t < NBC) sh[t] = bcnt[t];
    __syncthreads();
    if (t <= NBC) {
        int sum = 0;
        for (int j = 0; j < t && j < NBC; j++) sum += sh[j];
        if (t < NBC) { bbase[t] = sum; cursor[t] = sum; }
        else if (t == NBC) bbase[NBC] = sum;  // == E
    }
}

// ---------------- staged coalesced partition into coarse buckets ----------------
// packed = (src << 11) | (dst & 2047)

__global__ void k_passC(const int* __restrict__ src, const int* __restrict__ dst,
                        int* __restrict__ cursor, unsigned* __restrict__ packed,
                        int E, int NBC, int epb) {
    __shared__ unsigned stage[STILE];          // 32 KB
    __shared__ int hist[NBC_MAX], lb[NBC_MAX], gb[NBC_MAX], lcur[NBC_MAX];
    int bs = blockIdx.x * epb;
    int be = min(E, bs + epb);
    for (int tb = bs; tb < be; tb += STILE) {
        int te = min(be, tb + STILE);
        if (threadIdx.x < NBC_MAX) hist[threadIdx.x] = 0;
        __syncthreads();
        unsigned pk[EPT];
        int bkv[EPT];
#pragma unroll
        for (int u = 0; u < EPT; u++) {
            int i = tb + u * TPB + (int)threadIdx.x;
            if (i < te) {
                int d = dst[i];
                int b = d >> CSH;
                pk[u] = ((unsigned)src[i] << CSH) | (unsigned)(d & (CN - 1));
                bkv[u] = b;
                atomicAdd(&hist[b], 1);
            } else bkv[u] = -1;
        }
        __syncthreads();
        if (threadIdx.x < (unsigned)NBC) {
            int b = threadIdx.x;
            int sum = 0;
            for (int j = 0; j < b; j++) sum += hist[j];   // same-addr reads broadcast
            lb[b] = sum;
            lcur[b] = sum;
            gb[b] = atomicAdd(&cursor[b], hist[b]);
        }
        __syncthreads();
#pragma unroll
        for (int u = 0; u < EPT; u++) {
            if (bkv[u] >= 0) {
                int pos = atomicAdd(&lcur[bkv[u]], 1);
                stage[pos] = pk[u];
            }
        }
        __syncthreads();
        int wid = threadIdx.x >> 6, lane = threadIdx.x & 63;
        for (int b = wid; b < NBC; b += 4) {
            int len = hist[b], l = lb[b], g = gb[b];
            for (int i = lane; i < len; i += 64)
                packed[g + i] = stage[l + i];               // coalesced runs
        }
        __syncthreads();
    }
}

// ---------------- degrees from packed (per coarse bucket, S-split) ----------------

__global__ void k_degc(const unsigned* __restrict__ packed, const int* __restrict__ bbase,
                       int* __restrict__ deg, int SD, int N) {
    __shared__ int cnt[CN];
    for (int i = threadIdx.x; i < CN; i += TPB) cnt[i] = 0;
    __syncthreads();
    int b = blockIdx.x / SD, s = blockIdx.x - b * SD;
    int e0 = bbase[b], e1 = bbase[b + 1];
    int len = e1 - e0;
    int ce0 = e0 + (int)((long long)len * s / SD);
    int ce1 = e0 + (int)((long long)len * (s + 1) / SD);
    int e = ce0 + threadIdx.x;
    for (; e + 3 * TPB < ce1; e += 4 * TPB) {
        unsigned p0 = packed[e], p1 = packed[e + TPB], p2 = packed[e + 2 * TPB], p3 = packed[e + 3 * TPB];
        atomicAdd(&cnt[p0 & (CN - 1)], 1);
        atomicAdd(&cnt[p1 & (CN - 1)], 1);
        atomicAdd(&cnt[p2 & (CN - 1)], 1);
        atomicAdd(&cnt[p3 & (CN - 1)], 1);
    }
    for (; e < ce1; e += TPB)
        atomicAdd(&cnt[packed[e] & (CN - 1)], 1);
    __syncthreads();
    int node0 = b << CSH;
    for (int i = threadIdx.x; i < CN; i += TPB)
        if (cnt[i] && node0 + i < N) atomicAdd(&deg[node0 + i], cnt[i]);
}

// ---------------- node-parallel: dis = rsqrt(deg+1); xs = x*dis ----------------

__global__ void k_prepv(const float* __restrict__ x, const int* __restrict__ deg,
                        float* __restrict__ dis, float* __restrict__ xs, int N) {
    int v = blockIdx.x * blockDim.x + threadIdx.x;
    if (v >= N) return;
    float di = rsqrtf((float)(deg[v] + 1));  // +1 self-loop
    dis[v] = di;
    float4 xv = ((const float4*)x)[v];
    xv.x *= di; xv.y *= di; xv.z *= di; xv.w *= di;
    ((float4*)xs)[v] = xv;
}

// ---------------- layer-1 edge pass: aggregate xs into 2048-node LDS acc ----------------

#define U1 4

__global__ void k_agg1c(const unsigned* __restrict__ packed, const int* __restrict__ bbase,
                        const float* __restrict__ xs, float* __restrict__ partial1, int S1) {
    __shared__ float acc[CN * A1S];   // 40 KB
    for (int i = threadIdx.x; i < CN * A1S; i += TPB) acc[i] = 0.0f;
    __syncthreads();
    int b = blockIdx.x / S1, s = blockIdx.x - b * S1;
    int e0 = bbase[b], e1 = bbase[b + 1];
    int len = e1 - e0;
    int ce0 = e0 + (int)((long long)len * s / S1);
    int ce1 = e0 + (int)((long long)len * (s + 1) / S1);
    int e = ce0 + threadIdx.x;
    for (; e + (U1 - 1) * TPB < ce1; e += U1 * TPB) {
        unsigned pk[U1];
#pragma unroll
        for (int u = 0; u < U1; u++) pk[u] = packed[e + u * TPB];
        float4 m[U1];
#pragma unroll
        for (int u = 0; u < U1; u++) m[u] = ((const float4*)xs)[pk[u] >> CSH];
#pragma unroll
        for (int u = 0; u < U1; u++) {
            float* a = &acc[(pk[u] & (CN - 1)) * A1S];
            atomicAdd(a + 0, m[u].x);
            atomicAdd(a + 1, m[u].y);
            atomicAdd(a + 2, m[u].z);
            atomicAdd(a + 3, m[u].w);
        }
    }
    for (; e < ce1; e += TPB) {
        unsigned pk = packed[e];
        float4 m = ((const float4*)xs)[pk >> CSH];
        float* a = &acc[(pk & (CN - 1)) * A1S];
        atomicAdd(a + 0, m.x);
        atomicAdd(a + 1, m.y);
        atomicAdd(a + 2, m.z);
        atomicAdd(a + 3, m.w);
    }
    __syncthreads();
    float* p = partial1 + (size_t)blockIdx.x * (CN * 4);
    for (int i = threadIdx.x; i < CN * 4; i += TPB)
        p[i] = acc[(i >> 2) * A1S + (i & 3)];
}

// ---------------- layer-1 combine: (+self)*dis -> @W1+b1 -> relu -> @W2 -> *dis ----------------

__global__ void k_comb1(const float* __restrict__ partial1, const float* __restrict__ xs,
                        const float* __restrict__ dis, const float* __restrict__ W1,
                        const float* __restrict__ b1, const float* __restrict__ W2,
                        float* __restrict__ hs2, int S1, int N) {
    __shared__ float w1[64], w2[32], bb[16];
    if (threadIdx.x < 64) w1[threadIdx.x] = W1[threadIdx.x];
    if (threadIdx.x < 32) w2[threadIdx.x] = W2[threadIdx.x];
    if (threadIdx.x < 16) bb[threadIdx.x] = b1[threadIdx.x];
    __syncthreads();
    int v = blockIdx.x * blockDim.x + threadIdx.x;
    if (v >= N) return;
    int b = v >> CSH, lv = v & (CN - 1);
    float4 sum = ((const float4*)xs)[v];   // self-loop
    for (int s = 0; s < S1; s++) {
        float4 t = ((const float4*)partial1)[(size_t)(b * S1 + s) * CN + lv];
        sum.x += t.x; sum.y += t.y; sum.z += t.z; sum.w += t.w;
    }
    float di = dis[v];
    float v0 = sum.x * di, v1 = sum.y * di, v2 = sum.z * di, v3 = sum.w * di;
    float s0 = 0.f, s1 = 0.f;
#pragma unroll
    for (int j = 0; j < 16; j++) {
        float h = v0 * w1[j] + v1 * w1[16 + j] + v2 * w1[32 + j] + v3 * w1[48 + j] + bb[j];
        h = fmaxf(h, 0.0f);
        s0 += h * w2[2 * j];
        s1 += h * w2[2 * j + 1];
    }
    ((float2*)hs2)[v] = make_float2(s0 * di, s1 * di);
}

// ---------------- layer-2 edge pass ----------------

#define U2 4

__global__ void k_agg2c(const unsigned* __restrict__ packed, const int* __restrict__ bbase,
                        const float* __restrict__ hs2, float* __restrict__ partial2, int S2) {
    __shared__ float acc[CN * A2S];   // 24 KB
    for (int i = threadIdx.x; i < CN * A2S; i += TPB) acc[i] = 0.0f;
    __syncthreads();
    int b = blockIdx.x / S2, s = blockIdx.x - b * S2;
    int e0 = bbase[b], e1 = bbase[b + 1];
    int len = e1 - e0;
    int ce0 = e0 + (int)((long long)len * s / S2);
    int ce1 = e0 + (int)((long long)len * (s + 1) / S2);
    int e = ce0 + threadIdx.x;
    for (; e + (U2 - 1) * TPB < ce1; e += U2 * TPB) {
        unsigned pk[U2];
#pragma unroll
        for (int u = 0; u < U2; u++) pk[u] = packed[e + u * TPB];
        float2 m[U2];
#pragma unroll
        for (int u = 0; u < U2; u++) m[u] = ((const float2*)hs2)[pk[u] >> CSH];
#pragma unroll
        for (int u = 0; u < U2; u++) {
            float* a = &acc[(pk[u] & (CN - 1)) * A2S];
            atomicAdd(a + 0, m[u].x);
            atomicAdd(a + 1, m[u].y);
        }
    }
    for (; e < ce1; e += TPB) {
        unsigned pk = packed[e];
        float2 m = ((const float2*)hs2)[pk >> CSH];
        float* a = &acc[(pk & (CN - 1)) * A2S];
        atomicAdd(a + 0, m.x);
        atomicAdd(a + 1, m.y);
    }
    __syncthreads();
    float* p = partial2 + (size_t)blockIdx.x * (CN * 2);
    for (int i = threadIdx.x; i < CN * 2; i += TPB)
        p[i] = acc[(i >> 1) * A2S + (i & 1)];
}

// ---------------- layer-2 combine + final bias -> out ----------------

__global__ void k_comb2(const float* __restrict__ partial2, const float* __restrict__ hs2,
                        const float* __restrict__ dis, const float* __restrict__ b2,
                        float* __restrict__ out, int S2, int N) {
    int v = blockIdx.x * blockDim.x + threadIdx.x;
    if (v >= N) return;
    int b = v >> CSH, lv = v & (CN - 1);
    float2 sum = ((const float2*)hs2)[v];   // self-loop
    for (int s = 0; s < S2; s++) {
        float2 t = ((const float2*)partial2)[(size_t)(b * S2 + s) * CN + lv];
        sum.x += t.x; sum.y += t.y;
    }
    float di = dis[v];
    ((float2*)out)[v] = make_float2(sum.x * di + b2[0], sum.y * di + b2[1]);
}

// ---------------- fallback (R1 atomic pipeline) ----------------

__global__ void k_deg_fb(const int* __restrict__ dst, int* __restrict__ deg, int E) {
    int i = blockIdx.x * blockDim.x + threadIdx.x;
    if (i < E) atomicAdd(&deg[dst[i]], 1);
}
__global__ void k_dis_fb(const int* __restrict__ deg, float* __restrict__ dis, int N) {
    int v = blockIdx.x * blockDim.x + threadIdx.x;
    if (v < N) dis[v] = rsqrtf((float)(deg[v] + 1));
}
__global__ void k_lin1_fb(const float* __restrict__ x, const float* __restrict__ W1,
                          const float* __restrict__ dis, float* __restrict__ hs1,
                          float* __restrict__ agg1, int N) {
    __shared__ float w[64];
    if (threadIdx.x < 64) w[threadIdx.x] = W1[threadIdx.x];
    __syncthreads();
    int v = blockIdx.x * blockDim.x + threadIdx.x;
    if (v >= N) return;
    float4 xv = ((const float4*)x)[v];
    float d = dis[v];
#pragma unroll
    for (int j = 0; j < 16; j++) {
        float h = (xv.x * w[j] + xv.y * w[16 + j] + xv.z * w[32 + j] + xv.w * w[48 + j]) * d;
        hs1[v * 16 + j] = h;
        agg1[v * 16 + j] = h;
    }
}
__global__ void k_scat1_fb(const int* __restrict__ src, const int* __restrict__ dst,
                           const float* __restrict__ hs1, float* __restrict__ agg1, int E4) {
    int t = blockIdx.x * blockDim.x + threadIdx.x;
    if (t >= E4) return;
    int e = t >> 2, q = t & 3;
    int s = src[e], d = dst[e];
    float4 m = ((const float4*)hs1)[s * 4 + q];
    float* a = agg1 + (size_t)d * 16 + q * 4;
    atomicAdd(a + 0, m.x); atomicAdd(a + 1, m.y);
    atomicAdd(a + 2, m.z); atomicAdd(a + 3, m.w);
}
__global__ void k_lin2_fb(const float* __restrict__ agg1, const float* __restrict__ dis,
                          const float* __restrict__ b1, const float* __restrict__ W2,
                          float* __restrict__ hs2, float* __restrict__ agg2, int N) {
    __shared__ float w[32];
    __shared__ float bb[16];
    if (threadIdx.x < 32) w[threadIdx.x] = W2[threadIdx.x];
    if (threadIdx.x < 16) bb[threadIdx.x] = b1[threadIdx.x];
    __syncthreads();
    int v = blockIdx.x * blockDim.x + threadIdx.x;
    if (v >= N) return;
    float d = dis[v];
    float a0 = 0.f, a1 = 0.f;
#pragma unroll
    for (int k = 0; k < 16; k++) {
        float r = fmaxf(agg1[v * 16 + k] * d + bb[k], 0.0f);
        a0 += r * w[k * 2 + 0];
        a1 += r * w[k * 2 + 1];
    }
    float2 hv = make_float2(a0 * d, a1 * d);
    ((float2*)hs2)[v] = hv;
    ((float2*)agg2)[v] = hv;
}
__global__ void k_scat2_fb(const int* __restrict__ src, const int* __restrict__ dst,
                           const float* __restrict__ hs2, float* __restrict__ agg2, int E) {
    int e = blockIdx.x * blockDim.x + threadIdx.x;
    if (e >= E) return;
    int s = src[e], d = dst[e];
    float2 m = ((const float2*)hs2)[s];
    atomicAdd(&agg2[d * 2 + 0], m.x);
    atomicAdd(&agg2[d * 2 + 1], m.y);
}
__global__ void k_out_fb(const float* __restrict__ agg2, const float* __restrict__ dis,
                         const float* __restrict__ b2, float* __restrict__ out, int N) {
    int v = blockIdx.x * blockDim.x + threadIdx.x;
    if (v >= N) return;
    float d = dis[v];
    out[v * 2 + 0] = agg2[v * 2 + 0] * d + b2[0];
    out[v * 2 + 1] = agg2[v * 2 + 1] * d + b2[1];
}

// ---------------- launch ----------------

extern "C" void kernel_launch(void* const* d_in, const int* in_sizes, int n_in,
                              void* d_out, int out_size, void* d_ws, size_t ws_size,
                              hipStream_t stream) {
    const float* x  = (const float*)d_in[0];
    const int*   ei = (const int*)d_in[1];
    const float* W1 = (const float*)d_in[2];
    const float* b1 = (const float*)d_in[3];
    const float* W2 = (const float*)d_in[4];
    const float* b2 = (const float*)d_in[5];

    const int N = in_sizes[0] / 4;   // 100000
    const int E = in_sizes[1] / 2;   // 6400000
    const int* src = ei;
    const int* dst = ei + E;
    float* outp = (float*)d_out;

    auto align = [](size_t v) { return (v + 255) & ~(size_t)255; };
    const int NBC = (N + CN - 1) >> CSH;   // 49 coarse buckets for N=100k

    auto need_for = [&](int S1, int S2) {
        return align((size_t)E * 4)                       /* packed */
             + align((size_t)N * 4)                       /* dis */
             + align((size_t)N * 16)                      /* xs */
             + align((size_t)N * 8)                       /* hs2 */
             + align(((size_t)N + NBC) * 4)               /* deg + bcnt */
             + align((size_t)NBC * 4)                     /* cursor */
             + align((size_t)(NBC + 1) * 4)               /* bbase */
             + align((size_t)NBC * S1 * CN * 4 * 4)       /* partial1 */
             + align((size_t)NBC * S2 * CN * 2 * 4);      /* partial2 */
    };

    const int tiers[6][2] = {{8, 8}, {8, 4}, {4, 4}, {4, 2}, {2, 2}, {1, 1}};
    int S1 = 0, S2 = 0;
    for (int t = 0; t < 6; t++)
        if (need_for(tiers[t][0], tiers[t][1]) <= ws_size) { S1 = tiers[t][0]; S2 = tiers[t][1]; break; }

    // src must fit in 32-CSH bits of the packed word (64-bit arithmetic! R7 bug: 32-bit wrap -> always fallback)
    const bool src_fits = (size_t)N <= ((size_t)1 << (32 - CSH));

    if (S1 > 0 && NBC <= NBC_MAX && src_fits) {
        char* ws = (char*)d_ws;
        unsigned* packed = (unsigned*)ws; ws += align((size_t)E * 4);
        float* dis  = (float*)ws; ws += align((size_t)N * 4);
        float* xs   = (float*)ws; ws += align((size_t)N * 16);
        float* hs2  = (float*)ws; ws += align((size_t)N * 8);
        int* deg    = (int*)ws;   ws += align(((size_t)N + NBC) * 4);
        int* bcnt   = deg + N;    // contiguous with deg: zeroed together
        int* cursor = (int*)ws;   ws += align((size_t)NBC * 4);
        int* bbase  = (int*)ws;   ws += align((size_t)(NBC + 1) * 4);
        float* partial1 = (float*)ws; ws += align((size_t)NBC * S1 * CN * 4 * 4);
        float* partial2 = (float*)ws; ws += align((size_t)NBC * S2 * CN * 2 * 4);

        const int gN = (N + TPB - 1) / TPB;
        const int epb = STILE * 2;                 // 2 super-tiles per block
        const int gPC = (E + epb - 1) / epb;
        const int SD = 8;                          // degc split

        k_zero<<<(N + NBC + TPB - 1) / TPB, TPB, 0, stream>>>(deg, N + NBC);
        k_histc<<<512, TPB, 0, stream>>>(dst, bcnt, E, NBC);
        k_scanc<<<1, 128, 0, stream>>>(bcnt, bbase, cursor, NBC);
        k_passC<<<gPC, TPB, 0, stream>>>(src, dst, cursor, packed, E, NBC, epb);
        k_degc<<<NBC * SD, TPB, 0, stream>>>(packed, bbase, deg, SD, N);
        k_prepv<<<gN, TPB, 0, stream>>>(x, deg, dis, xs, N);
        k_agg1c<<<NBC * S1, TPB, 0, stream>>>(packed, bbase, xs, partial1, S1);
        k_comb1<<<gN, TPB, 0, stream>>>(partial1, xs, dis, W1, b1, W2, hs2, S1, N);
        k_agg2c<<<NBC * S2, TPB, 0, stream>>>(packed, bbase, hs2, partial2, S2);
        k_comb2<<<gN, TPB, 0, stream>>>(partial2, hs2, dis, b2, outp, S2, N);
    } else {
        // fallback: R1 atomic-scatter pipeline
        char* ws = (char*)d_ws;
        int*   deg  = (int*)ws;   ws += align((size_t)N * 4);
        float* dis  = (float*)ws; ws += align((size_t)N * 4);
        float* hs1  = (float*)ws; ws += align((size_t)N * 16 * 4);
        float* agg1 = (float*)ws; ws += align((size_t)N * 16 * 4);
        float* hs2  = (float*)ws; ws += align((size_t)N * 2 * 4);
        float* agg2 = (float*)ws; ws += align((size_t)N * 2 * 4);
        int gN = (N + TPB - 1) / TPB;
        int gE = (E + TPB - 1) / TPB;
        int gE4 = ((size_t)E * 4 + TPB - 1) / TPB;

        k_zero<<<gN, TPB, 0, stream>>>(deg, N);
        k_deg_fb<<<gE, TPB, 0, stream>>>(dst, deg, E);
        k_dis_fb<<<gN, TPB, 0, stream>>>(deg, dis, N);
        k_lin1_fb<<<gN, TPB, 0, stream>>>(x, W1, dis, hs1, agg1, N);
        k_scat1_fb<<<gE4, TPB, 0, stream>>>(src, dst, hs1, agg1, E * 4);
        k_lin2_fb<<<gN, TPB, 0, stream>>>(agg1, dis, b1, W2, hs2, agg2, N);
        k_scat2_fb<<<gE, TPB, 0, stream>>>(src, dst, hs2, agg2, E);
        k_out_fb<<<gN, TPB, 0, stream>>>(agg2, dis, b2, outp, N);
    }
}

// Round 9
// 419.549 us; speedup vs baseline: 5.3421x; 1.0515x over previous
//
#include <hip/hip_runtime.h>

#define TPB 256
#define CSH 10                 // nodes per coarse bucket = 1024
#define CN 1024
#define NBC_MAX 128            // max coarse buckets supported by fast path
#define STILE 8192             // edges per super-tile in passC
#define EPT (STILE / TPB)      // 32 edges per thread
#define A1S 5                  // layer-1 LDS acc stride (gcd(5,32)=1)
#define A2S 3                  // layer-2 LDS acc stride

// ---------------- small utils ----------------

__global__ void k_zero(int* __restrict__ p, int n) {
    int i = blockIdx.x * blockDim.x + threadIdx.x;
    if (i < n) p[i] = 0;
}

// ---------------- coarse histogram over dst ----------------

__global__ void k_histc(const int* __restrict__ dst, int* __restrict__ bcnt, int E, int NBC) {
    __shared__ int cnt[NBC_MAX];
    if (threadIdx.x < NBC_MAX) cnt[threadIdx.x] = 0;
    __syncthreads();
    int per = (E + gridDim.x - 1) / gridDim.x;
    int s = blockIdx.x * per;
    int e = min(E, s + per);
    for (int i = s + threadIdx.x; i < e; i += TPB)
        atomicAdd(&cnt[dst[i] >> CSH], 1);
    __syncthreads();
    if (threadIdx.x < (unsigned)NBC && cnt[threadIdx.x])
        atomicAdd(&bcnt[threadIdx.x], cnt[threadIdx.x]);
}

// ---------------- exclusive scan of <=128 bucket counts ----------------

__global__ void k_scanc(const int* __restrict__ bcnt, int* __restrict__ bbase,
                        int* __restrict__ cursor, int NBC) {
    __shared__ int sh[NBC_MAX];
    int t = threadIdx.x;
    if (t < NBC) sh[t] = bcnt[t];
    __syncthreads();
    if (t <= NBC) {
        int sum = 0;
        for (int j = 0; j < t && j < NBC; j++) sum += sh[j];
        if (t < NBC) { bbase[t] = sum; cursor[t] = sum; }
        else if (t == NBC) bbase[NBC] = sum;  // == E
    }
}

// ---------------- staged coalesced partition into coarse buckets ----------------
// packed = (src << CSH) | (dst & (CN-1))

__global__ void k_passC(const int* __restrict__ src, const int* __restrict__ dst,
                        int* __restrict__ cursor, unsigned* __restrict__ packed,
                        int E, int NBC, int epb) {
    __shared__ unsigned stage[STILE];          // 32 KB
    __shared__ int hist[NBC_MAX], lb[NBC_MAX], gb[NBC_MAX], lcur[NBC_MAX];
    int bs = blockIdx.x * epb;
    int be = min(E, bs + epb);
    for (int tb = bs; tb < be; tb += STILE) {
        int te = min(be, tb + STILE);
        if (threadIdx.x < NBC_MAX) hist[threadIdx.x] = 0;
        __syncthreads();
        unsigned pk[EPT];
        int bkv[EPT];
#pragma unroll
        for (int u = 0; u < EPT; u++) {
            int i = tb + u * TPB + (int)threadIdx.x;
            if (i < te) {
                int d = dst[i];
                int b = d >> CSH;
                pk[u] = ((unsigned)src[i] << CSH) | (unsigned)(d & (CN - 1));
                bkv[u] = b;
                atomicAdd(&hist[b], 1);
            } else bkv[u] = -1;
        }
        __syncthreads();
        if (threadIdx.x < (unsigned)NBC) {
            int b = threadIdx.x;
            int sum = 0;
            for (int j = 0; j < b; j++) sum += hist[j];   // same-addr reads broadcast
            lb[b] = sum;
            lcur[b] = sum;
            gb[b] = atomicAdd(&cursor[b], hist[b]);
        }
        __syncthreads();
#pragma unroll
        for (int u = 0; u < EPT; u++) {
            if (bkv[u] >= 0) {
                int pos = atomicAdd(&lcur[bkv[u]], 1);
                stage[pos] = pk[u];
            }
        }
        __syncthreads();
        int wid = threadIdx.x >> 6, lane = threadIdx.x & 63;
        for (int b = wid; b < NBC; b += 4) {
            int len = hist[b], l = lb[b], g = gb[b];
            for (int i = lane; i < len; i += 64)
                packed[g + i] = stage[l + i];               // coalesced runs
        }
        __syncthreads();
    }
}

// ---------------- degrees from packed (per coarse bucket, S-split) ----------------

__global__ void k_degc(const unsigned* __restrict__ packed, const int* __restrict__ bbase,
                       int* __restrict__ deg, int SD, int N) {
    __shared__ int cnt[CN];
    for (int i = threadIdx.x; i < CN; i += TPB) cnt[i] = 0;
    __syncthreads();
    int b = blockIdx.x / SD, s = blockIdx.x - b * SD;
    int e0 = bbase[b], e1 = bbase[b + 1];
    int len = e1 - e0;
    int ce0 = e0 + (int)((long long)len * s / SD);
    int ce1 = e0 + (int)((long long)len * (s + 1) / SD);
    int e = ce0 + threadIdx.x;
    for (; e + 3 * TPB < ce1; e += 4 * TPB) {
        unsigned p0 = packed[e], p1 = packed[e + TPB], p2 = packed[e + 2 * TPB], p3 = packed[e + 3 * TPB];
        atomicAdd(&cnt[p0 & (CN - 1)], 1);
        atomicAdd(&cnt[p1 & (CN - 1)], 1);
        atomicAdd(&cnt[p2 & (CN - 1)], 1);
        atomicAdd(&cnt[p3 & (CN - 1)], 1);
    }
    for (; e < ce1; e += TPB)
        atomicAdd(&cnt[packed[e] & (CN - 1)], 1);
    __syncthreads();
    int node0 = b << CSH;
    for (int i = threadIdx.x; i < CN; i += TPB)
        if (cnt[i] && node0 + i < N) atomicAdd(&deg[node0 + i], cnt[i]);
}

// ---------------- node-parallel: dis = rsqrt(deg+1); xs = x*dis ----------------

__global__ void k_prepv(const float* __restrict__ x, const int* __restrict__ deg,
                        float* __restrict__ dis, float* __restrict__ xs, int N) {
    int v = blockIdx.x * blockDim.x + threadIdx.x;
    if (v >= N) return;
    float di = rsqrtf((float)(deg[v] + 1));  // +1 self-loop
    dis[v] = di;
    float4 xv = ((const float4*)x)[v];
    xv.x *= di; xv.y *= di; xv.z *= di; xv.w *= di;
    ((float4*)xs)[v] = xv;
}

// ---------------- layer-1 edge pass: aggregate xs into 1024-node LDS acc ----------------

#define U1 4

__global__ void k_agg1c(const unsigned* __restrict__ packed, const int* __restrict__ bbase,
                        const float* __restrict__ xs, float* __restrict__ partial1, int S1) {
    __shared__ float acc[CN * A1S];   // 20 KB
    for (int i = threadIdx.x; i < CN * A1S; i += TPB) acc[i] = 0.0f;
    __syncthreads();
    int b = blockIdx.x / S1, s = blockIdx.x - b * S1;
    int e0 = bbase[b], e1 = bbase[b + 1];
    int len = e1 - e0;
    int ce0 = e0 + (int)((long long)len * s / S1);
    int ce1 = e0 + (int)((long long)len * (s + 1) / S1);
    int e = ce0 + threadIdx.x;
    for (; e + (U1 - 1) * TPB < ce1; e += U1 * TPB) {
        unsigned pk[U1];
#pragma unroll
        for (int u = 0; u < U1; u++) pk[u] = packed[e + u * TPB];
        float4 m[U1];
#pragma unroll
        for (int u = 0; u < U1; u++) m[u] = ((const float4*)xs)[pk[u] >> CSH];
#pragma unroll
        for (int u = 0; u < U1; u++) {
            float* a = &acc[(pk[u] & (CN - 1)) * A1S];
            atomicAdd(a + 0, m[u].x);
            atomicAdd(a + 1, m[u].y);
            atomicAdd(a + 2, m[u].z);
            atomicAdd(a + 3, m[u].w);
        }
    }
    for (; e < ce1; e += TPB) {
        unsigned pk = packed[e];
        float4 m = ((const float4*)xs)[pk >> CSH];
        float* a = &acc[(pk & (CN - 1)) * A1S];
        atomicAdd(a + 0, m.x);
        atomicAdd(a + 1, m.y);
        atomicAdd(a + 2, m.z);
        atomicAdd(a + 3, m.w);
    }
    __syncthreads();
    float* p = partial1 + (size_t)blockIdx.x * (CN * 4);
    for (int i = threadIdx.x; i < CN * 4; i += TPB)
        p[i] = acc[(i >> 2) * A1S + (i & 3)];
}

// ---------------- layer-1 combine: (+self)*dis -> @W1+b1 -> relu -> @W2 -> *dis ----------------

__global__ void k_comb1(const float* __restrict__ partial1, const float* __restrict__ xs,
                        const float* __restrict__ dis, const float* __restrict__ W1,
                        const float* __restrict__ b1, const float* __restrict__ W2,
                        float* __restrict__ hs2, int S1, int N) {
    __shared__ float w1[64], w2[32], bb[16];
    if (threadIdx.x < 64) w1[threadIdx.x] = W1[threadIdx.x];
    if (threadIdx.x < 32) w2[threadIdx.x] = W2[threadIdx.x];
    if (threadIdx.x < 16) bb[threadIdx.x] = b1[threadIdx.x];
    __syncthreads();
    int v = blockIdx.x * blockDim.x + threadIdx.x;
    if (v >= N) return;
    int b = v >> CSH, lv = v & (CN - 1);
    float4 sum = ((const float4*)xs)[v];   // self-loop
    for (int s = 0; s < S1; s++) {
        float4 t = ((const float4*)partial1)[(size_t)(b * S1 + s) * CN + lv];
        sum.x += t.x; sum.y += t.y; sum.z += t.z; sum.w += t.w;
    }
    float di = dis[v];
    float v0 = sum.x * di, v1 = sum.y * di, v2 = sum.z * di, v3 = sum.w * di;
    float s0 = 0.f, s1 = 0.f;
#pragma unroll
    for (int j = 0; j < 16; j++) {
        float h = v0 * w1[j] + v1 * w1[16 + j] + v2 * w1[32 + j] + v3 * w1[48 + j] + bb[j];
        h = fmaxf(h, 0.0f);
        s0 += h * w2[2 * j];
        s1 += h * w2[2 * j + 1];
    }
    ((float2*)hs2)[v] = make_float2(s0 * di, s1 * di);
}

// ---------------- layer-2 edge pass ----------------

#define U2 4

__global__ void k_agg2c(const unsigned* __restrict__ packed, const int* __restrict__ bbase,
                        const float* __restrict__ hs2, float* __restrict__ partial2, int S2) {
    __shared__ float acc[CN * A2S];   // 12 KB
    for (int i = threadIdx.x; i < CN * A2S; i += TPB) acc[i] = 0.0f;
    __syncthreads();
    int b = blockIdx.x / S2, s = blockIdx.x - b * S2;
    int e0 = bbase[b], e1 = bbase[b + 1];
    int len = e1 - e0;
    int ce0 = e0 + (int)((long long)len * s / S2);
    int ce1 = e0 + (int)((long long)len * (s + 1) / S2);
    int e = ce0 + threadIdx.x;
    for (; e + (U2 - 1) * TPB < ce1; e += U2 * TPB) {
        unsigned pk[U2];
#pragma unroll
        for (int u = 0; u < U2; u++) pk[u] = packed[e + u * TPB];
        float2 m[U2];
#pragma unroll
        for (int u = 0; u < U2; u++) m[u] = ((const float2*)hs2)[pk[u] >> CSH];
#pragma unroll
        for (int u = 0; u < U2; u++) {
            float* a = &acc[(pk[u] & (CN - 1)) * A2S];
            atomicAdd(a + 0, m[u].x);
            atomicAdd(a + 1, m[u].y);
        }
    }
    for (; e < ce1; e += TPB) {
        unsigned pk = packed[e];
        float2 m = ((const float2*)hs2)[pk >> CSH];
        float* a = &acc[(pk & (CN - 1)) * A2S];
        atomicAdd(a + 0, m.x);
        atomicAdd(a + 1, m.y);
    }
    __syncthreads();
    float* p = partial2 + (size_t)blockIdx.x * (CN * 2);
    for (int i = threadIdx.x; i < CN * 2; i += TPB)
        p[i] = acc[(i >> 1) * A2S + (i & 1)];
}

// ---------------- layer-2 combine + final bias -> out ----------------

__global__ void k_comb2(const float* __restrict__ partial2, const float* __restrict__ hs2,
                        const float* __restrict__ dis, const float* __restrict__ b2,
                        float* __restrict__ out, int S2, int N) {
    int v = blockIdx.x * blockDim.x + threadIdx.x;
    if (v >= N) return;
    int b = v >> CSH, lv = v & (CN - 1);
    float2 sum = ((const float2*)hs2)[v];   // self-loop
    for (int s = 0; s < S2; s++) {
        float2 t = ((const float2*)partial2)[(size_t)(b * S2 + s) * CN + lv];
        sum.x += t.x; sum.y += t.y;
    }
    float di = dis[v];
    ((float2*)out)[v] = make_float2(sum.x * di + b2[0], sum.y * di + b2[1]);
}

// ---------------- fallback (R1 atomic pipeline) ----------------

__global__ void k_deg_fb(const int* __restrict__ dst, int* __restrict__ deg, int E) {
    int i = blockIdx.x * blockDim.x + threadIdx.x;
    if (i < E) atomicAdd(&deg[dst[i]], 1);
}
__global__ void k_dis_fb(const int* __restrict__ deg, float* __restrict__ dis, int N) {
    int v = blockIdx.x * blockDim.x + threadIdx.x;
    if (v < N) dis[v] = rsqrtf((float)(deg[v] + 1));
}
__global__ void k_lin1_fb(const float* __restrict__ x, const float* __restrict__ W1,
                          const float* __restrict__ dis, float* __restrict__ hs1,
                          float* __restrict__ agg1, int N) {
    __shared__ float w[64];
    if (threadIdx.x < 64) w[threadIdx.x] = W1[threadIdx.x];
    __syncthreads();
    int v = blockIdx.x * blockDim.x + threadIdx.x;
    if (v >= N) return;
    float4 xv = ((const float4*)x)[v];
    float d = dis[v];
#pragma unroll
    for (int j = 0; j < 16; j++) {
        float h = (xv.x * w[j] + xv.y * w[16 + j] + xv.z * w[32 + j] + xv.w * w[48 + j]) * d;
        hs1[v * 16 + j] = h;
        agg1[v * 16 + j] = h;
    }
}
__global__ void k_scat1_fb(const int* __restrict__ src, const int* __restrict__ dst,
                           const float* __restrict__ hs1, float* __restrict__ agg1, int E4) {
    int t = blockIdx.x * blockDim.x + threadIdx.x;
    if (t >= E4) return;
    int e = t >> 2, q = t & 3;
    int s = src[e], d = dst[e];
    float4 m = ((const float4*)hs1)[s * 4 + q];
    float* a = agg1 + (size_t)d * 16 + q * 4;
    atomicAdd(a + 0, m.x); atomicAdd(a + 1, m.y);
    atomicAdd(a + 2, m.z); atomicAdd(a + 3, m.w);
}
__global__ void k_lin2_fb(const float* __restrict__ agg1, const float* __restrict__ dis,
                          const float* __restrict__ b1, const float* __restrict__ W2,
                          float* __restrict__ hs2, float* __restrict__ agg2, int N) {
    __shared__ float w[32];
    __shared__ float bb[16];
    if (threadIdx.x < 32) w[threadIdx.x] = W2[threadIdx.x];
    if (threadIdx.x < 16) bb[threadIdx.x] = b1[threadIdx.x];
    __syncthreads();
    int v = blockIdx.x * blockDim.x + threadIdx.x;
    if (v >= N) return;
    float d = dis[v];
    float a0 = 0.f, a1 = 0.f;
#pragma unroll
    for (int k = 0; k < 16; k++) {
        float r = fmaxf(agg1[v * 16 + k] * d + bb[k], 0.0f);
        a0 += r * w[k * 2 + 0];
        a1 += r * w[k * 2 + 1];
    }
    float2 hv = make_float2(a0 * d, a1 * d);
    ((float2*)hs2)[v] = hv;
    ((float2*)agg2)[v] = hv;
}
__global__ void k_scat2_fb(const int* __restrict__ src, const int* __restrict__ dst,
                           const float* __restrict__ hs2, float* __restrict__ agg2, int E) {
    int e = blockIdx.x * blockDim.x + threadIdx.x;
    if (e >= E) return;
    int s = src[e], d = dst[e];
    float2 m = ((const float2*)hs2)[s];
    atomicAdd(&agg2[d * 2 + 0], m.x);
    atomicAdd(&agg2[d * 2 + 1], m.y);
}
__global__ void k_out_fb(const float* __restrict__ agg2, const float* __restrict__ dis,
                         const float* __restrict__ b2, float* __restrict__ out, int N) {
    int v = blockIdx.x * blockDim.x + threadIdx.x;
    if (v >= N) return;
    float d = dis[v];
    out[v * 2 + 0] = agg2[v * 2 + 0] * d + b2[0];
    out[v * 2 + 1] = agg2[v * 2 + 1] * d + b2[1];
}

// ---------------- launch ----------------

extern "C" void kernel_launch(void* const* d_in, const int* in_sizes, int n_in,
                              void* d_out, int out_size, void* d_ws, size_t ws_size,
                              hipStream_t stream) {
    const float* x  = (const float*)d_in[0];
    const int*   ei = (const int*)d_in[1];
    const float* W1 = (const float*)d_in[2];
    const float* b1 = (const float*)d_in[3];
    const float* W2 = (const float*)d_in[4];
    const float* b2 = (const float*)d_in[5];

    const int N = in_sizes[0] / 4;   // 100000
    const int E = in_sizes[1] / 2;   // 6400000
    const int* src = ei;
    const int* dst = ei + E;
    float* outp = (float*)d_out;

    auto align = [](size_t v) { return (v + 255) & ~(size_t)255; };
    const int NBC = (N + CN - 1) >> CSH;   // 98 coarse buckets for N=100k

    auto need_for = [&](int S1, int S2) {
        return align((size_t)E * 4)                       /* packed */
             + align((size_t)N * 4)                       /* dis */
             + align((size_t)N * 16)                      /* xs */
             + align((size_t)N * 8)                       /* hs2 */
             + align(((size_t)N + NBC) * 4)               /* deg + bcnt */
             + align((size_t)NBC * 4)                     /* cursor */
             + align((size_t)(NBC + 1) * 4)               /* bbase */
             + align((size_t)NBC * S1 * CN * 4 * 4)       /* partial1 */
             + align((size_t)NBC * S2 * CN * 2 * 4);      /* partial2 */
    };

    const int tiers[7][2] = {{16, 16}, {16, 8}, {8, 8}, {8, 4}, {4, 4}, {2, 2}, {1, 1}};
    int S1 = 0, S2 = 0;
    for (int t = 0; t < 7; t++)
        if (need_for(tiers[t][0], tiers[t][1]) <= ws_size) { S1 = tiers[t][0]; S2 = tiers[t][1]; break; }

    // src must fit in 32-CSH bits of packed (64-bit arithmetic — R7's 32-bit wrap bug)
    const bool src_fits = (size_t)N <= ((size_t)1 << (32 - CSH));

    if (S1 > 0 && NBC <= NBC_MAX && src_fits) {
        char* ws = (char*)d_ws;
        unsigned* packed = (unsigned*)ws; ws += align((size_t)E * 4);
        float* dis  = (float*)ws; ws += align((size_t)N * 4);
        float* xs   = (float*)ws; ws += align((size_t)N * 16);
        float* hs2  = (float*)ws; ws += align((size_t)N * 8);
        int* deg    = (int*)ws;   ws += align(((size_t)N + NBC) * 4);
        int* bcnt   = deg + N;    // contiguous with deg: zeroed together
        int* cursor = (int*)ws;   ws += align((size_t)NBC * 4);
        int* bbase  = (int*)ws;   ws += align((size_t)(NBC + 1) * 4);
        float* partial1 = (float*)ws; ws += align((size_t)NBC * S1 * CN * 4 * 4);
        float* partial2 = (float*)ws; ws += align((size_t)NBC * S2 * CN * 2 * 4);

        const int gN = (N + TPB - 1) / TPB;
        const int epb = STILE * 2;                 // 2 super-tiles per block
        const int gPC = (E + epb - 1) / epb;
        const int SD = 8;                          // degc split

        k_zero<<<(N + NBC + TPB - 1) / TPB, TPB, 0, stream>>>(deg, N + NBC);
        k_histc<<<512, TPB, 0, stream>>>(dst, bcnt, E, NBC);
        k_scanc<<<1, 256, 0, stream>>>(bcnt, bbase, cursor, NBC);
        k_passC<<<gPC, TPB, 0, stream>>>(src, dst, cursor, packed, E, NBC, epb);
        k_degc<<<NBC * SD, TPB, 0, stream>>>(packed, bbase, deg, SD, N);
        k_prepv<<<gN, TPB, 0, stream>>>(x, deg, dis, xs, N);
        k_agg1c<<<NBC * S1, TPB, 0, stream>>>(packed, bbase, xs, partial1, S1);
        k_comb1<<<gN, TPB, 0, stream>>>(partial1, xs, dis, W1, b1, W2, hs2, S1, N);
        k_agg2c<<<NBC * S2, TPB, 0, stream>>>(packed, bbase, hs2, partial2, S2);
        k_comb2<<<gN, TPB, 0, stream>>>(partial2, hs2, dis, b2, outp, S2, N);
    } else {
        // fallback: R1 atomic-scatter pipeline
        char* ws = (char*)d_ws;
        int*   deg  = (int*)ws;   ws += align((size_t)N * 4);
        float* dis  = (float*)ws; ws += align((size_t)N * 4);
        float* hs1  = (float*)ws; ws += align((size_t)N * 16 * 4);
        float* agg1 = (float*)ws; ws += align((size_t)N * 16 * 4);
        float* hs2  = (float*)ws; ws += align((size_t)N * 2 * 4);
        float* agg2 = (float*)ws; ws += align((size_t)N * 2 * 4);
        int gN = (N + TPB - 1) / TPB;
        int gE = (E + TPB - 1) / TPB;
        int gE4 = ((size_t)E * 4 + TPB - 1) / TPB;

        k_zero<<<gN, TPB, 0, stream>>>(deg, N);
        k_deg_fb<<<gE, TPB, 0, stream>>>(dst, deg, E);
        k_dis_fb<<<gN, TPB, 0, stream>>>(deg, dis, N);
        k_lin1_fb<<<gN, TPB, 0, stream>>>(x, W1, dis, hs1, agg1, N);
        k_scat1_fb<<<gE4, TPB, 0, stream>>>(src, dst, hs1, agg1, E * 4);
        k_lin2_fb<<<gN, TPB, 0, stream>>>(agg1, dis, b1, W2, hs2, agg2, N);
        k_scat2_fb<<<gE, TPB, 0, stream>>>(src, dst, hs2, agg2, E);
        k_out_fb<<<gN, TPB, 0, stream>>>(agg2, dis, b2, outp, N);
    }
}